// Round 4
// baseline (277.230 us; speedup 1.0000x reference)
//
#include <hip/hip_runtime.h>

// NCC loss: five 9x9x9 box sums (I, J, I^2, J^2, I*J), stride 1, pad 4,
// count_include_pad (divisor 729), ncc = cov^2/(varI*varJ+eps), out = -mean.
// Shapes fixed: [2,1,192,192,192] fp32.
//
// R4: LDS-instruction diet. x-sums computed straight from GLOBAL float4 loads
// in registers (96 "x-task" threads, 4 outputs each via sliding window) --
// deletes the stage-write + x-read LDS phases that made R3 LDS-bound
// (~1480 -> ~750 ds-cycles per block-slice). xs double-buffered -> ONE
// barrier per slice; next slice's global loads issued after x-phase, consumed
// after the following y-phase (latency hidden). z via register shift (R3).

#define S    192
#define SS   (S * S)
#define TX   16
#define TY   16
#define KZ   32
#define RAD  4
#define WIN  9
#define NSL  (KZ + 2 * RAD)      // 40
#define HXR  (TY + 2 * RAD)      // 24 halo rows
#define XSW  (TX + 1)            // 17 (pad)
#define NVOX (2.0 * S * S * S)

__global__ void ncc_init(double* ws) { ws[0] = 0.0; }

__global__ void ncc_final(const double* __restrict__ ws, float* __restrict__ out) {
    out[0] = (float)(-ws[0] / NVOX);
}

__global__ __launch_bounds__(256, 4) void ncc_main(const float* __restrict__ I,
                                                   const float* __restrict__ J,
                                                   double* __restrict__ ws) {
    // LDS ~16.3 KB: xs4 2*24*17*16 + xs1 2*24*17*4 + red
    __shared__ float4 xs4[2][HXR][XSW];
    __shared__ float  xs1[2][HXR][XSW];
    __shared__ float  red[4];

    const int tx  = threadIdx.x;
    const int ty  = threadIdx.y;
    const int tid = ty * TX + tx;

    const int bz = blockIdx.z;               // 0..11
    const int b  = (bz >= 6) ? 1 : 0;
    const int zc = bz - 6 * b;
    const int x0 = blockIdx.x * TX;
    const int y0 = blockIdx.y * TY;
    const int z0 = zc * KZ;

    const float* Ib = I + (size_t)b * S * SS;
    const float* Jb = J + (size_t)b * S * SS;

    // x-task: 96 threads, task (row xr 0..23, quad xq 0..3) -> 4 outputs.
    // Input cols c0..c0+11; each float4 chunk is all-valid or all-invalid
    // (c0 multiple of 4, bounds multiples of 4).
    const bool xtask = (tid < 4 * HXR);
    const int  xr  = tid >> 2;
    const int  xq  = tid & 3;
    const int  gy  = y0 - RAD + xr;
    const bool gyv = ((unsigned)gy < (unsigned)S);
    const int  c0  = x0 + 4 * xq - RAD;
    const bool cv0 = gyv && ((unsigned)(c0    ) < (unsigned)S);
    const bool cv1 = gyv && ((unsigned)(c0 + 4) < (unsigned)S);
    const bool cv2 = gyv && ((unsigned)(c0 + 8) < (unsigned)S);
    const size_t rowoff = gyv ? ((size_t)gy * S + c0) : 0;

    float4 li0, li1, li2, lj0, lj1, lj2;

    auto load_slice = [&](int p) {
        li0 = li1 = li2 = lj0 = lj1 = lj2 = make_float4(0.f, 0.f, 0.f, 0.f);
        if (p < NSL) {
            const int zi = z0 - RAD + p;
            if (xtask && ((unsigned)zi < (unsigned)S)) {
                const float* rI = Ib + (size_t)zi * SS + rowoff;
                const float* rJ = Jb + (size_t)zi * SS + rowoff;
                if (cv0) { li0 = *(const float4*)(rI);     lj0 = *(const float4*)(rJ); }
                if (cv1) { li1 = *(const float4*)(rI + 4); lj1 = *(const float4*)(rJ + 4); }
                if (cv2) { li2 = *(const float4*)(rI + 8); lj2 = *(const float4*)(rJ + 8); }
            }
        }
    };

    // x-phase: sliding 9-tap sums over 12 inputs -> 4 outputs, 5 fields.
    // Squares/products fused into fmas (no stored product arrays -> low VGPR).
    auto xphase = [&](int p) {
        if (xtask) {
            const float iv[12] = { li0.x, li0.y, li0.z, li0.w,
                                   li1.x, li1.y, li1.z, li1.w,
                                   li2.x, li2.y, li2.z, li2.w };
            const float jv[12] = { lj0.x, lj0.y, lj0.z, lj0.w,
                                   lj1.x, lj1.y, lj1.z, lj1.w,
                                   lj2.x, lj2.y, lj2.z, lj2.w };
            float a = 0.f, bb = 0.f, c = 0.f, d = 0.f, e = 0.f;
            #pragma unroll
            for (int m = 0; m < WIN; ++m) {
                a += iv[m];
                bb += jv[m];
                c = fmaf(iv[m], iv[m], c);
                d = fmaf(jv[m], jv[m], d);
                e = fmaf(iv[m], jv[m], e);
            }
            const int cb = p & 1;
            #pragma unroll
            for (int k = 0; k < 4; ++k) {
                if (k > 0) {
                    a += iv[8 + k] - iv[k - 1];
                    bb += jv[8 + k] - jv[k - 1];
                    c += fmaf(iv[8 + k], iv[8 + k], -iv[k - 1] * iv[k - 1]);
                    d += fmaf(jv[8 + k], jv[8 + k], -jv[k - 1] * jv[k - 1]);
                    e += fmaf(iv[8 + k], jv[8 + k], -iv[k - 1] * jv[k - 1]);
                }
                xs4[cb][xr][4 * xq + k] = make_float4(a, bb, c, d);
                xs1[cb][xr][4 * xq + k] = e;
            }
        }
    };

    // z shift registers (phase-free, static indices -> VGPRs; R3-proven).
    float d_[5][WIN];
    #pragma unroll
    for (int f = 0; f < 5; ++f)
        #pragma unroll
        for (int k = 0; k < WIN; ++k)
            d_[f][k] = 0.f;

    float run0 = 0.f, run1 = 0.f, run2 = 0.f, run3 = 0.f, run4 = 0.f;
    float acc = 0.f;

    auto yphase = [&](int p) {
        const int pb = p & 1;
        float4 s4 = make_float4(0.f, 0.f, 0.f, 0.f);
        float  s1 = 0.f;
        #pragma unroll
        for (int dy = 0; dy < WIN; ++dy) {
            const float4 v = xs4[pb][ty + dy][tx];
            s4.x += v.x; s4.y += v.y; s4.z += v.z; s4.w += v.w;
            s1 += xs1[pb][ty + dy][tx];
        }
        run0 += s4.x - d_[0][0];
        run1 += s4.y - d_[1][0];
        run2 += s4.z - d_[2][0];
        run3 += s4.w - d_[3][0];
        run4 += s1   - d_[4][0];
        #pragma unroll
        for (int k = 0; k < WIN - 1; ++k) {
            d_[0][k] = d_[0][k + 1];
            d_[1][k] = d_[1][k + 1];
            d_[2][k] = d_[2][k + 1];
            d_[3][k] = d_[3][k + 1];
            d_[4][k] = d_[4][k + 1];
        }
        d_[0][WIN - 1] = s4.x;
        d_[1][WIN - 1] = s4.y;
        d_[2][WIN - 1] = s4.z;
        d_[3][WIN - 1] = s4.w;
        d_[4][WIN - 1] = s1;
        if (p >= 2 * RAD) {
            const float inv = 1.0f / 729.0f;
            const float mI  = run0 * inv;
            const float mJ  = run1 * inv;
            const float vI  = run2 * inv - mI * mI;
            const float vJ  = run3 * inv - mJ * mJ;
            const float cIJ = run4 * inv - mI * mJ;
            acc += (cIJ * cIJ) / (vI * vJ + 1e-5f);
        }
    };

    // Pipeline: [y(p-1) | x(p) -> xs[p&1] | load p+1 | barrier] per iter.
    // y reads xs[(p-1)&1], x writes xs[p&1] -> disjoint, no intra-iter
    // barrier; the end barrier separates x-write(p) from y-read(p).
    load_slice(0);
    xphase(0);
    load_slice(1);
    __syncthreads();

    #pragma unroll 1
    for (int idx = 1; idx < NSL; ++idx) {
        yphase(idx - 1);
        xphase(idx);
        load_slice(idx + 1);
        __syncthreads();
    }
    yphase(NSL - 1);

    // Block reduction: wave shuffle -> LDS -> one double atomic
    float v = acc;
    #pragma unroll
    for (int off = 32; off >= 1; off >>= 1)
        v += __shfl_down(v, off, 64);
    const int lane = tid & 63;
    const int wid  = tid >> 6;
    if (lane == 0) red[wid] = v;
    __syncthreads();
    if (tid == 0) {
        atomicAdd(ws, (double)(red[0] + red[1] + red[2] + red[3]));
    }
}

extern "C" void kernel_launch(void* const* d_in, const int* in_sizes, int n_in,
                              void* d_out, int out_size, void* d_ws, size_t ws_size,
                              hipStream_t stream) {
    const float* I = (const float*)d_in[0];   // y_pred
    const float* J = (const float*)d_in[1];   // y_true
    double* ws = (double*)d_ws;
    float* out = (float*)d_out;

    hipLaunchKernelGGL(ncc_init, dim3(1), dim3(1), 0, stream, ws);

    dim3 grid(S / TX, S / TY, 6 * 2);   // 12 x 12 x 12 = 1728 blocks
    dim3 blk(TX, TY);                   // 256 threads
    hipLaunchKernelGGL(ncc_main, grid, blk, 0, stream, I, J, ws);

    hipLaunchKernelGGL(ncc_final, dim3(1), dim3(1), 0, stream, ws, out);
}